// Round 13
// baseline (169.186 us; speedup 1.0000x reference)
//
#include <hip/hip_runtime.h>

#define NN 50000
#define NE 640000
#define DF 128
#define BSH 8
#define BWD 256                          // nodes per bucket
#define NBKT 196                         // ceil(NN/BWD)
#define BSTRIDE 8192                     // per-bucket capacity (mean 3265)
#define CPAD 16                          // ints per global counter (one 64B line)
#define EPB 8192                         // edges per scatter block
#define NSB ((NE + EPB - 1) / EPB)       // 79 scatter blocks
#define MROWS 50048                      // 782*64 padded rows
#define GG 782                           // gemm row tiles

typedef __attribute__((ext_vector_type(8))) short short8;
typedef __attribute__((ext_vector_type(4))) float f32x4;

__device__ inline unsigned bf16rne(float f) {
  unsigned u = __float_as_uint(f);
  return (u + 0x7fff + ((u >> 16) & 1)) >> 16;
}
__device__ inline float bflo(unsigned u) { return __uint_as_float(u << 16); }
__device__ inline float bfhi(unsigned u) { return __uint_as_float(u & 0xffff0000u); }

// ---------------- wpack + gfill zero ----------------
// B-frag: lane l holds W[k=kc*32+(l>>4)*8+j][col=ct*16+(l&15)], j=0..7.

__global__ __launch_bounds__(256) void k_wz(const float* __restrict__ W1, const float* __restrict__ W2,
                                            uint4* __restrict__ whf, uint4* __restrict__ wlf,
                                            int* __restrict__ gfill) {
  if (blockIdx.x == 16) {
    for (int i = threadIdx.x; i < NBKT * CPAD; i += 256) gfill[i] = 0;
    return;
  }
  int idx = blockIdx.x * 256 + threadIdx.x;  // 0..4095
  int m = idx >> 11;
  int r = idx & 2047;
  int ct = r >> 8, kc = (r >> 6) & 3, l = r & 63;
  const float* W = m ? W2 : W1;
  unsigned hi[8], lo[8];
#pragma unroll
  for (int j = 0; j < 8; ++j) {
    int k = kc * 32 + (l >> 4) * 8 + j;
    int c = ct * 16 + (l & 15);
    float w = W[k * DF + c];
    unsigned h = bf16rne(w);
    hi[j] = h;
    lo[j] = bf16rne(w - bflo(h));
  }
  uint4 H, L;
  H.x = hi[0] | (hi[1] << 16); H.y = hi[2] | (hi[3] << 16);
  H.z = hi[4] | (hi[5] << 16); H.w = hi[6] | (hi[7] << 16);
  L.x = lo[0] | (lo[1] << 16); L.y = lo[2] | (lo[3] << 16);
  L.z = lo[4] | (lo[5] << 16); L.w = lo[6] | (lo[7] << 16);
  whf[idx] = H;
  wlf[idx] = L;
}

// ---------------- fused: bucketed scatter  ||  gemm1 (hA = bf16(X@W1)) ----------------

struct ScatSh {
  int cnt[NBKT], cur[NBKT], gbase[NBKT];
  int scan[256];
  unsigned stage[EPB];
};
struct GemmSh { float Ep[4][16][132]; };
union SgSh { ScatSh s; GemmSh g; };

__global__ __launch_bounds__(256) void k_sg(const int* __restrict__ ei, int* __restrict__ gfill,
                                            unsigned* __restrict__ pairs,
                                            const float* __restrict__ X,
                                            const uint4* __restrict__ whf, const uint4* __restrict__ wlf,
                                            unsigned* __restrict__ hA) {
  __shared__ SgSh sh;
  int t = threadIdx.x;

  if (blockIdx.x < NSB) {
    // ---------- scatter: 8192 edges -> bucket-grouped pairs ----------
    int e0 = blockIdx.x * EPB;
    for (int i = t; i < NBKT; i += 256) sh.s.cnt[i] = 0;
    __syncthreads();

    unsigned pk[32];
    int bk[32];
#pragma unroll
    for (int i = 0; i < 32; ++i) {
      int e = e0 + i * 256 + t;
      if (e < NE) {
        int s = ei[e], d = ei[NE + e];
        bk[i] = d >> BSH;
        pk[i] = (unsigned)s | ((unsigned)(d & (BWD - 1)) << 16);
        atomicAdd(&sh.s.cnt[bk[i]], 1);
      } else {
        bk[i] = -1;
      }
    }
    __syncthreads();

    int v = (t < NBKT) ? sh.s.cnt[t] : 0;
    sh.s.scan[t] = v;
    __syncthreads();
    for (int d = 1; d < 256; d <<= 1) {
      int x2 = (t >= d) ? sh.s.scan[t - d] : 0;
      __syncthreads();
      sh.s.scan[t] += x2;
      __syncthreads();
    }
    if (t < NBKT) {
      int start = sh.s.scan[t] - v;
      sh.s.cnt[t] = start;
      sh.s.cur[t] = start;
      sh.s.gbase[t] = (v > 0) ? atomicAdd(&gfill[t * CPAD], v) : 0;
    }
    __syncthreads();

#pragma unroll
    for (int i = 0; i < 32; ++i) {
      if (bk[i] >= 0) {
        int pos = atomicAdd(&sh.s.cur[bk[i]], 1);
        sh.s.stage[pos] = pk[i];
      }
    }
    __syncthreads();

    int wv = t >> 6, ln = t & 63;
    for (int b = wv; b < NBKT; b += 4) {
      int start = sh.s.cnt[b];
      int end = sh.s.cur[b];
      int gb = sh.s.gbase[b];
      unsigned* pb = pairs + (size_t)b * BSTRIDE;
      for (int i = start + ln; i < end; i += 64) {
        int go = gb + (i - start);
        if (go < BSTRIDE) pb[go] = sh.s.stage[i];
      }
    }
  } else {
    // ---------- gemm1: MFMA hi/lo, f32 A ----------
    int w = t >> 6, l = t & 63;
    int brow = (blockIdx.x - NSB) * 64 + w * 16;
    int ra = brow + (l & 15);
    bool inb = ra < NN;

    short8 Ah[4], Al[4];
#pragma unroll
    for (int kc = 0; kc < 4; ++kc) {
      float f[8] = {0.f, 0.f, 0.f, 0.f, 0.f, 0.f, 0.f, 0.f};
      if (inb) {
        const float* A = X + (size_t)ra * DF + kc * 32 + (l >> 4) * 8;
        float4 p = *(const float4*)A;
        float4 qq = *(const float4*)(A + 4);
        f[0] = p.x; f[1] = p.y; f[2] = p.z; f[3] = p.w;
        f[4] = qq.x; f[5] = qq.y; f[6] = qq.z; f[7] = qq.w;
      }
      unsigned hh[8], ll[8];
#pragma unroll
      for (int j = 0; j < 8; ++j) {
        hh[j] = bf16rne(f[j]);
        ll[j] = bf16rne(f[j] - bflo(hh[j]));
      }
      uint4 H, L;
      H.x = hh[0] | (hh[1] << 16); H.y = hh[2] | (hh[3] << 16);
      H.z = hh[4] | (hh[5] << 16); H.w = hh[6] | (hh[7] << 16);
      L.x = ll[0] | (ll[1] << 16); L.y = ll[2] | (ll[3] << 16);
      L.z = ll[4] | (ll[5] << 16); L.w = ll[6] | (ll[7] << 16);
      Ah[kc] = *(short8*)&H;
      Al[kc] = *(short8*)&L;
    }

    f32x4 acc[8];
#pragma unroll
    for (int ct = 0; ct < 8; ++ct) acc[ct] = f32x4{0.f, 0.f, 0.f, 0.f};

#pragma unroll
    for (int kc = 0; kc < 4; ++kc) {
#pragma unroll
      for (int ct = 0; ct < 8; ++ct) {
        int fi = (ct * 4 + kc) * 64 + l;
        uint4 wh4 = whf[fi];
        uint4 wl4 = wlf[fi];
        short8 wh = *(short8*)&wh4;
        short8 wl = *(short8*)&wl4;
        acc[ct] = __builtin_amdgcn_mfma_f32_16x16x32_bf16(Ah[kc], wh, acc[ct], 0, 0, 0);
        acc[ct] = __builtin_amdgcn_mfma_f32_16x16x32_bf16(Ah[kc], wl, acc[ct], 0, 0, 0);
        acc[ct] = __builtin_amdgcn_mfma_f32_16x16x32_bf16(Al[kc], wh, acc[ct], 0, 0, 0);
      }
    }

#pragma unroll
    for (int ct = 0; ct < 8; ++ct)
#pragma unroll
      for (int reg = 0; reg < 4; ++reg)
        sh.g.Ep[w][(l >> 4) * 4 + reg][ct * 16 + (l & 15)] = acc[ct][reg];

    int r16 = l >> 2, cc = (l & 3) * 32;
    int R = (blockIdx.x - NSB) * 64 + w * 16 + r16;
    float sc = (R < NN) ? 1.f : 0.f;
    unsigned ub[16];
#pragma unroll
    for (int i = 0; i < 16; ++i) {
      float f0 = sh.g.Ep[w][r16][cc + 2 * i] * sc;
      float f1 = sh.g.Ep[w][r16][cc + 2 * i + 1] * sc;
      ub[i] = bf16rne(f0) | (bf16rne(f1) << 16);
    }
    uint4* co = (uint4*)(hA + (size_t)R * 64 + (cc >> 1));
    co[0] = make_uint4(ub[0], ub[1], ub[2], ub[3]);
    co[1] = make_uint4(ub[4], ub[5], ub[6], ub[7]);
    co[2] = make_uint4(ub[8], ub[9], ub[10], ub[11]);
    co[3] = make_uint4(ub[12], ub[13], ub[14], ub[15]);
  }
}

// ---------------- build: inline bucket-prefix + LDS counting sort ----------------

__global__ __launch_bounds__(256) void k_build(const unsigned* __restrict__ pairs,
                                               const int* __restrict__ gfill,
                                               int* __restrict__ off, float* __restrict__ dinv,
                                               unsigned short* __restrict__ ssrc) {
  __shared__ int lcnt[BWD];
  __shared__ int lfill[BWD];
  __shared__ int s[BWD];
  __shared__ int red[256];
  __shared__ unsigned short stage[BSTRIDE];
  int b = blockIdx.x, t = threadIdx.x;

  int part = 0;
  for (int j = t; j < b; j += 256) part += min(gfill[j * CPAD], BSTRIDE);
  red[t] = part;
  __syncthreads();
  for (int d = 128; d > 0; d >>= 1) {
    if (t < d) red[t] += red[t + d];
    __syncthreads();
  }
  int e0 = red[0];
  int n = min(gfill[b * CPAD], BSTRIDE);
  const unsigned* pb = pairs + (size_t)b * BSTRIDE;

  lcnt[t] = 0;
  __syncthreads();
  for (int i = t; i < n; i += 256) atomicAdd(&lcnt[pb[i] >> 16], 1);
  __syncthreads();

  int cnt = lcnt[t];
  s[t] = cnt;
  __syncthreads();
  for (int d = 1; d < 256; d <<= 1) {
    int x = (t >= d) ? s[t - d] : 0;
    __syncthreads();
    s[t] += x;
    __syncthreads();
  }
  int node = b * BWD + t;
  int ex = s[t] - cnt;
  lfill[t] = ex;
  if (node < NN) {
    off[node] = e0 + ex;
    dinv[node] = rsqrtf((float)(cnt + 1));  // +1 self-loop
  }
  if (node == NN - 1) off[NN] = NE;
  __syncthreads();

  for (int i = t; i < n; i += 256) {
    unsigned p = pb[i];
    int pos = atomicAdd(&lfill[p >> 16], 1);
    stage[pos] = (unsigned short)(p & 0xffffu);
  }
  __syncthreads();
  for (int i = t; i < n; i += 256) ssrc[e0 + i] = stage[i];
}

// ---------------- fused agg1 + gemm2: act stays in LDS; hB = dinv*(act@W2) ----------------

__global__ __launch_bounds__(256) void k_aggemm(const unsigned* __restrict__ hA,
                                                const float* __restrict__ dinv,
                                                const int* __restrict__ off,
                                                const unsigned short* __restrict__ ssrc,
                                                const float* __restrict__ b1,
                                                const uint4* __restrict__ whf,
                                                const uint4* __restrict__ wlf,
                                                unsigned* __restrict__ hB) {
  __shared__ unsigned actS[64][68];
  __shared__ float Ep[4][16][132];
  int t = threadIdx.x, w = t >> 6, l = t & 63;
  int brow = blockIdx.x * 64;
  int c = l & 15, q = l >> 4;

  // ---- phase 1: aggregate 64 nodes into actS (wave per node, 16 iters) ----
  for (int it = 0; it < 16; ++it) {
    int r = it * 4 + w;
    int g = brow + r;
    if (g < NN) {
      float di = dinv[g];
      float acc[8];
      uint4 u0 = *((const uint4*)(hA + (size_t)g * 64) + c);
      float m = (q == 0) ? di : 0.f;  // self term weight dinv[g] (x di at the end -> di^2)
      acc[0] = bflo(u0.x) * m; acc[1] = bfhi(u0.x) * m;
      acc[2] = bflo(u0.y) * m; acc[3] = bfhi(u0.y) * m;
      acc[4] = bflo(u0.z) * m; acc[5] = bfhi(u0.z) * m;
      acc[6] = bflo(u0.w) * m; acc[7] = bfhi(u0.w) * m;

      int e = off[g], e1 = off[g + 1];
      for (int eb0 = e; eb0 < e1; eb0 += 8) {
        int ea = eb0 + q, eb = eb0 + 4 + q;
        int sa = (ea < e1) ? (int)ssrc[ea] : NN;
        int sb = (eb < e1) ? (int)ssrc[eb] : NN;
        float wa = (ea < e1) ? dinv[sa] : 0.f;
        float wb = (eb < e1) ? dinv[sb] : 0.f;
        uint4 ua = *((const uint4*)(hA + (size_t)sa * 64) + c);
        uint4 ub = *((const uint4*)(hA + (size_t)sb * 64) + c);
        acc[0] = fmaf(bflo(ua.x), wa, acc[0]); acc[1] = fmaf(bfhi(ua.x), wa, acc[1]);
        acc[2] = fmaf(bflo(ua.y), wa, acc[2]); acc[3] = fmaf(bfhi(ua.y), wa, acc[3]);
        acc[4] = fmaf(bflo(ua.z), wa, acc[4]); acc[5] = fmaf(bfhi(ua.z), wa, acc[5]);
        acc[6] = fmaf(bflo(ua.w), wa, acc[6]); acc[7] = fmaf(bfhi(ua.w), wa, acc[7]);
        acc[0] = fmaf(bflo(ub.x), wb, acc[0]); acc[1] = fmaf(bfhi(ub.x), wb, acc[1]);
        acc[2] = fmaf(bflo(ub.y), wb, acc[2]); acc[3] = fmaf(bfhi(ub.y), wb, acc[3]);
        acc[4] = fmaf(bflo(ub.z), wb, acc[4]); acc[5] = fmaf(bfhi(ub.z), wb, acc[5]);
        acc[6] = fmaf(bflo(ub.w), wb, acc[6]); acc[7] = fmaf(bfhi(ub.w), wb, acc[7]);
      }

#pragma unroll
      for (int j = 0; j < 8; ++j) {
        acc[j] += __shfl_xor(acc[j], 16);
        acc[j] += __shfl_xor(acc[j], 32);
      }

      if (q < 2) {
        int col0 = c * 8 + q * 4;
        float4 b4 = *(const float4*)(b1 + col0);
        float o0 = fmaxf(fmaf(acc[q * 4 + 0], di, b4.x), 0.f);
        float o1 = fmaxf(fmaf(acc[q * 4 + 1], di, b4.y), 0.f);
        float o2 = fmaxf(fmaf(acc[q * 4 + 2], di, b4.z), 0.f);
        float o3 = fmaxf(fmaf(acc[q * 4 + 3], di, b4.w), 0.f);
        uint2 p;
        p.x = bf16rne(o0) | (bf16rne(o1) << 16);
        p.y = bf16rne(o2) | (bf16rne(o3) << 16);
        *(uint2*)&actS[r][c * 4 + q * 2] = p;
      }
    } else {
      if (q < 2) *(uint2*)&actS[r][c * 4 + q * 2] = make_uint2(0u, 0u);
    }
  }
  __syncthreads();

  // ---- phase 2: gemm2 from actS ----
  short8 Ah[4];
  int lr = w * 16 + (l & 15);
#pragma unroll
  for (int kc = 0; kc < 4; ++kc) {
    uint4 u = *(const uint4*)&actS[lr][(kc * 4 + (l >> 4)) * 4];
    Ah[kc] = *(short8*)&u;
  }

  f32x4 acc2[8];
#pragma unroll
  for (int ct = 0; ct < 8; ++ct) acc2[ct] = f32x4{0.f, 0.f, 0.f, 0.f};

#pragma unroll
  for (int kc = 0; kc < 4; ++kc) {
#pragma unroll
    for (int ct = 0; ct < 8; ++ct) {
      int fi = (ct * 4 + kc) * 64 + l;
      uint4 wh4 = whf[fi];
      uint4 wl4 = wlf[fi];
      short8 wh = *(short8*)&wh4;
      short8 wl = *(short8*)&wl4;
      acc2[ct] = __builtin_amdgcn_mfma_f32_16x16x32_bf16(Ah[kc], wh, acc2[ct], 0, 0, 0);
      acc2[ct] = __builtin_amdgcn_mfma_f32_16x16x32_bf16(Ah[kc], wl, acc2[ct], 0, 0, 0);
    }
  }

#pragma unroll
  for (int ct = 0; ct < 8; ++ct)
#pragma unroll
    for (int reg = 0; reg < 4; ++reg)
      Ep[w][(l >> 4) * 4 + reg][ct * 16 + (l & 15)] = acc2[ct][reg];

  int r16 = l >> 2, cc = (l & 3) * 32;
  int R = brow + w * 16 + r16;
  float sc = (R < NN) ? dinv[R] : 0.f;
  unsigned ub[16];
#pragma unroll
  for (int i = 0; i < 16; ++i) {
    float f0 = Ep[w][r16][cc + 2 * i] * sc;
    float f1 = Ep[w][r16][cc + 2 * i + 1] * sc;
    ub[i] = bf16rne(f0) | (bf16rne(f1) << 16);
  }
  uint4* co = (uint4*)(hB + (size_t)R * 64 + (cc >> 1));
  co[0] = make_uint4(ub[0], ub[1], ub[2], ub[3]);
  co[1] = make_uint4(ub[4], ub[5], ub[6], ub[7]);
  co[2] = make_uint4(ub[8], ub[9], ub[10], ub[11]);
  co[3] = make_uint4(ub[12], ub[13], ub[14], ub[15]);
}

// ---------------- agg2: weightless gather (hB prescaled), f32 out ----------------

__global__ __launch_bounds__(256) void k_agg2(const unsigned* __restrict__ h, const float* __restrict__ dinv,
                                              const int* __restrict__ off, const unsigned short* __restrict__ ssrc,
                                              const float* __restrict__ bias, float* __restrict__ out) {
  int gw = (blockIdx.x * 256 + threadIdx.x) >> 6;
  int lane = threadIdx.x & 63;
  if (gw >= NN) return;

  int c = lane & 15;
  int q = lane >> 4;

  float acc[8];
  {
    uint4 u = *((const uint4*)(h + (size_t)gw * 64) + c);
    float m = (q == 0) ? 1.f : 0.f;
    acc[0] = bflo(u.x) * m; acc[1] = bfhi(u.x) * m;
    acc[2] = bflo(u.y) * m; acc[3] = bfhi(u.y) * m;
    acc[4] = bflo(u.z) * m; acc[5] = bfhi(u.z) * m;
    acc[6] = bflo(u.w) * m; acc[7] = bfhi(u.w) * m;
  }

  int e = off[gw], e1 = off[gw + 1];
  for (int e0 = e; e0 < e1; e0 += 8) {
    int ea = e0 + q;
    int eb = e0 + 4 + q;
    int sa = (ea < e1) ? (int)ssrc[ea] : NN;
    int sb = (eb < e1) ? (int)ssrc[eb] : NN;
    uint4 ua = *((const uint4*)(h + (size_t)sa * 64) + c);
    uint4 ub = *((const uint4*)(h + (size_t)sb * 64) + c);
    acc[0] += bflo(ua.x); acc[1] += bfhi(ua.x);
    acc[2] += bflo(ua.y); acc[3] += bfhi(ua.y);
    acc[4] += bflo(ua.z); acc[5] += bfhi(ua.z);
    acc[6] += bflo(ua.w); acc[7] += bfhi(ua.w);
    acc[0] += bflo(ub.x); acc[1] += bfhi(ub.x);
    acc[2] += bflo(ub.y); acc[3] += bfhi(ub.y);
    acc[4] += bflo(ub.z); acc[5] += bfhi(ub.z);
    acc[6] += bflo(ub.w); acc[7] += bfhi(ub.w);
  }

#pragma unroll
  for (int j = 0; j < 8; ++j) {
    acc[j] += __shfl_xor(acc[j], 16);
    acc[j] += __shfl_xor(acc[j], 32);
  }

  if (q < 2) {
    float di = dinv[gw];
    int col0 = c * 8 + q * 4;
    float4 b4 = *(const float4*)(bias + col0);
    float4 o;
    o.x = fmaf(acc[q * 4 + 0], di, b4.x);
    o.y = fmaf(acc[q * 4 + 1], di, b4.y);
    o.z = fmaf(acc[q * 4 + 2], di, b4.z);
    o.w = fmaf(acc[q * 4 + 3], di, b4.w);
    *(float4*)(out + (size_t)gw * DF + col0) = o;
  }
}

// ---------------- launcher ----------------

extern "C" void kernel_launch(void* const* d_in, const int* in_sizes, int n_in,
                              void* d_out, int out_size, void* d_ws, size_t ws_size,
                              hipStream_t stream) {
  const float* x  = (const float*)d_in[0];
  const int*   ei = (const int*)d_in[1];
  const float* W1 = (const float*)d_in[2];
  const float* b1 = (const float*)d_in[3];
  const float* W2 = (const float*)d_in[4];
  const float* b2 = (const float*)d_in[5];
  float* out = (float*)d_out;

  char* ws = (char*)d_ws;
  unsigned* hA    = (unsigned*)ws; ws += (size_t)MROWS * 64 * 4;        // bf16(X@W1), unscaled
  unsigned* hB    = (unsigned*)ws; ws += (size_t)MROWS * 64 * 4;        // dinv*(act@W2)
  unsigned* pairs = (unsigned*)ws; ws += (size_t)NBKT * BSTRIDE * 4;    // 6.4 MB bucket staging
  uint4* whf = (uint4*)ws;  ws += (size_t)4096 * 16;
  uint4* wlf = (uint4*)ws;  ws += (size_t)4096 * 16;
  int*   off  = (int*)ws;   ws += (size_t)(NN + 1) * 4;
  int*   gfill= (int*)ws;   ws += (size_t)NBKT * CPAD * 4;
  float* dinv = (float*)ws; ws += (size_t)NN * 4;
  unsigned short* ssrc = (unsigned short*)ws; ws += ((size_t)NE + 16) * 2;

  k_wz<<<17, 256, 0, stream>>>(W1, W2, whf, wlf, gfill);
  k_sg<<<NSB + GG, 256, 0, stream>>>(ei, gfill, pairs, x, whf, wlf, hA);
  k_build<<<NBKT, 256, 0, stream>>>(pairs, gfill, off, dinv, ssrc);
  k_aggemm<<<GG, 256, 0, stream>>>(hA, dinv, off, ssrc, b1, whf + 2048, wlf + 2048, hB);
  k_agg2<<<(NN * 64 + 255) / 256, 256, 0, stream>>>(hB, dinv, off, ssrc, b2, out);
}

// Round 14
// 123.952 us; speedup vs baseline: 1.3649x; 1.3649x over previous
//
#include <hip/hip_runtime.h>

#define NN 50000
#define NE 640000
#define DF 128
#define BSH 8
#define BWD 256                          // nodes per bucket
#define NBKT 196                         // ceil(NN/BWD)
#define BSTRIDE 8192                     // per-bucket capacity (mean 3265)
#define CPAD 16                          // ints per global counter (one 64B line)
#define EPB 8192                         // edges per scatter block
#define NSB ((NE + EPB - 1) / EPB)       // 79 scatter blocks
#define MROWS 50048                      // 782*64 padded rows
#define GG 782                           // gemm row tiles

typedef __attribute__((ext_vector_type(8))) short short8;
typedef __attribute__((ext_vector_type(4))) float f32x4;

__device__ inline unsigned bf16rne(float f) {
  unsigned u = __float_as_uint(f);
  return (u + 0x7fff + ((u >> 16) & 1)) >> 16;
}
__device__ inline float bflo(unsigned u) { return __uint_as_float(u << 16); }
__device__ inline float bfhi(unsigned u) { return __uint_as_float(u & 0xffff0000u); }

// ---------------- wpack + gfill zero ----------------

__global__ __launch_bounds__(256) void k_wz(const float* __restrict__ W1, const float* __restrict__ W2,
                                            uint4* __restrict__ whf, uint4* __restrict__ wlf,
                                            int* __restrict__ gfill) {
  if (blockIdx.x == 16) {
    for (int i = threadIdx.x; i < NBKT * CPAD; i += 256) gfill[i] = 0;
    return;
  }
  int idx = blockIdx.x * 256 + threadIdx.x;  // 0..4095
  int m = idx >> 11;
  int r = idx & 2047;
  int ct = r >> 8, kc = (r >> 6) & 3, l = r & 63;
  const float* W = m ? W2 : W1;
  unsigned hi[8], lo[8];
#pragma unroll
  for (int j = 0; j < 8; ++j) {
    int k = kc * 32 + (l >> 4) * 8 + j;
    int c = ct * 16 + (l & 15);
    float w = W[k * DF + c];
    unsigned h = bf16rne(w);
    hi[j] = h;
    lo[j] = bf16rne(w - bflo(h));
  }
  uint4 H, L;
  H.x = hi[0] | (hi[1] << 16); H.y = hi[2] | (hi[3] << 16);
  H.z = hi[4] | (hi[5] << 16); H.w = hi[6] | (hi[7] << 16);
  L.x = lo[0] | (lo[1] << 16); L.y = lo[2] | (lo[3] << 16);
  L.z = lo[4] | (lo[5] << 16); L.w = lo[6] | (lo[7] << 16);
  whf[idx] = H;
  wlf[idx] = L;
}

// ---------------- fused: bucketed scatter || gemm1 (hA = bf16(X@W1), unscaled) ----------------

struct ScatSh {
  int cnt[NBKT], cur[NBKT], gbase[NBKT];
  int scan[256];
  unsigned stage[EPB];
};
struct GemmSh { float Ep[4][16][132]; };
union SgSh { ScatSh s; GemmSh g; };

__global__ __launch_bounds__(256) void k_sg(const int* __restrict__ ei, int* __restrict__ gfill,
                                            unsigned* __restrict__ pairs,
                                            const float* __restrict__ X,
                                            const uint4* __restrict__ whf, const uint4* __restrict__ wlf,
                                            unsigned* __restrict__ hA) {
  __shared__ SgSh sh;
  int t = threadIdx.x;

  if (blockIdx.x < NSB) {
    int e0 = blockIdx.x * EPB;
    for (int i = t; i < NBKT; i += 256) sh.s.cnt[i] = 0;
    __syncthreads();

    unsigned pk[32];
    int bk[32];
#pragma unroll
    for (int i = 0; i < 32; ++i) {
      int e = e0 + i * 256 + t;
      if (e < NE) {
        int s = ei[e], d = ei[NE + e];
        bk[i] = d >> BSH;
        pk[i] = (unsigned)s | ((unsigned)(d & (BWD - 1)) << 16);
        atomicAdd(&sh.s.cnt[bk[i]], 1);
      } else {
        bk[i] = -1;
      }
    }
    __syncthreads();

    int v = (t < NBKT) ? sh.s.cnt[t] : 0;
    sh.s.scan[t] = v;
    __syncthreads();
    for (int d = 1; d < 256; d <<= 1) {
      int x2 = (t >= d) ? sh.s.scan[t - d] : 0;
      __syncthreads();
      sh.s.scan[t] += x2;
      __syncthreads();
    }
    if (t < NBKT) {
      int start = sh.s.scan[t] - v;
      sh.s.cnt[t] = start;
      sh.s.cur[t] = start;
      sh.s.gbase[t] = (v > 0) ? atomicAdd(&gfill[t * CPAD], v) : 0;
    }
    __syncthreads();

#pragma unroll
    for (int i = 0; i < 32; ++i) {
      if (bk[i] >= 0) {
        int pos = atomicAdd(&sh.s.cur[bk[i]], 1);
        sh.s.stage[pos] = pk[i];
      }
    }
    __syncthreads();

    int wv = t >> 6, ln = t & 63;
    for (int b = wv; b < NBKT; b += 4) {
      int start = sh.s.cnt[b];
      int end = sh.s.cur[b];
      int gb = sh.s.gbase[b];
      unsigned* pb = pairs + (size_t)b * BSTRIDE;
      for (int i = start + ln; i < end; i += 64) {
        int go = gb + (i - start);
        if (go < BSTRIDE) pb[go] = sh.s.stage[i];
      }
    }
  } else {
    // gemm1: MFMA hi/lo, f32 A, unscaled bf16 out
    int w = t >> 6, l = t & 63;
    int brow = (blockIdx.x - NSB) * 64 + w * 16;
    int ra = brow + (l & 15);
    bool inb = ra < NN;

    short8 Ah[4], Al[4];
#pragma unroll
    for (int kc = 0; kc < 4; ++kc) {
      float f[8] = {0.f, 0.f, 0.f, 0.f, 0.f, 0.f, 0.f, 0.f};
      if (inb) {
        const float* A = X + (size_t)ra * DF + kc * 32 + (l >> 4) * 8;
        float4 p = *(const float4*)A;
        float4 qq = *(const float4*)(A + 4);
        f[0] = p.x; f[1] = p.y; f[2] = p.z; f[3] = p.w;
        f[4] = qq.x; f[5] = qq.y; f[6] = qq.z; f[7] = qq.w;
      }
      unsigned hh[8], ll[8];
#pragma unroll
      for (int j = 0; j < 8; ++j) {
        hh[j] = bf16rne(f[j]);
        ll[j] = bf16rne(f[j] - bflo(hh[j]));
      }
      uint4 H, L;
      H.x = hh[0] | (hh[1] << 16); H.y = hh[2] | (hh[3] << 16);
      H.z = hh[4] | (hh[5] << 16); H.w = hh[6] | (hh[7] << 16);
      L.x = ll[0] | (ll[1] << 16); L.y = ll[2] | (ll[3] << 16);
      L.z = ll[4] | (ll[5] << 16); L.w = ll[6] | (ll[7] << 16);
      Ah[kc] = *(short8*)&H;
      Al[kc] = *(short8*)&L;
    }

    f32x4 acc[8];
#pragma unroll
    for (int ct = 0; ct < 8; ++ct) acc[ct] = f32x4{0.f, 0.f, 0.f, 0.f};

#pragma unroll
    for (int kc = 0; kc < 4; ++kc) {
#pragma unroll
      for (int ct = 0; ct < 8; ++ct) {
        int fi = (ct * 4 + kc) * 64 + l;
        uint4 wh4 = whf[fi];
        uint4 wl4 = wlf[fi];
        short8 wh = *(short8*)&wh4;
        short8 wl = *(short8*)&wl4;
        acc[ct] = __builtin_amdgcn_mfma_f32_16x16x32_bf16(Ah[kc], wh, acc[ct], 0, 0, 0);
        acc[ct] = __builtin_amdgcn_mfma_f32_16x16x32_bf16(Ah[kc], wl, acc[ct], 0, 0, 0);
        acc[ct] = __builtin_amdgcn_mfma_f32_16x16x32_bf16(Al[kc], wh, acc[ct], 0, 0, 0);
      }
    }

#pragma unroll
    for (int ct = 0; ct < 8; ++ct)
#pragma unroll
      for (int reg = 0; reg < 4; ++reg)
        sh.g.Ep[w][(l >> 4) * 4 + reg][ct * 16 + (l & 15)] = acc[ct][reg];

    int r16 = l >> 2, cc = (l & 3) * 32;
    int R = (blockIdx.x - NSB) * 64 + w * 16 + r16;
    float sc = (R < NN) ? 1.f : 0.f;
    unsigned ub[16];
#pragma unroll
    for (int i = 0; i < 16; ++i) {
      float f0 = sh.g.Ep[w][r16][cc + 2 * i] * sc;
      float f1 = sh.g.Ep[w][r16][cc + 2 * i + 1] * sc;
      ub[i] = bf16rne(f0) | (bf16rne(f1) << 16);
    }
    uint4* co = (uint4*)(hA + (size_t)R * 64 + (cc >> 1));
    co[0] = make_uint4(ub[0], ub[1], ub[2], ub[3]);
    co[1] = make_uint4(ub[4], ub[5], ub[6], ub[7]);
    co[2] = make_uint4(ub[8], ub[9], ub[10], ub[11]);
    co[3] = make_uint4(ub[12], ub[13], ub[14], ub[15]);
  }
}

// ---------------- build: inline bucket-prefix + LDS counting sort ----------------

__global__ __launch_bounds__(256) void k_build(const unsigned* __restrict__ pairs,
                                               const int* __restrict__ gfill,
                                               int* __restrict__ off, float* __restrict__ dinv,
                                               unsigned short* __restrict__ ssrc) {
  __shared__ int lcnt[BWD];
  __shared__ int lfill[BWD];
  __shared__ int s[BWD];
  __shared__ int red[256];
  __shared__ unsigned short stage[BSTRIDE];
  int b = blockIdx.x, t = threadIdx.x;

  int part = 0;
  for (int j = t; j < b; j += 256) part += min(gfill[j * CPAD], BSTRIDE);
  red[t] = part;
  __syncthreads();
  for (int d = 128; d > 0; d >>= 1) {
    if (t < d) red[t] += red[t + d];
    __syncthreads();
  }
  int e0 = red[0];
  int n = min(gfill[b * CPAD], BSTRIDE);
  const unsigned* pb = pairs + (size_t)b * BSTRIDE;

  lcnt[t] = 0;
  __syncthreads();
  for (int i = t; i < n; i += 256) atomicAdd(&lcnt[pb[i] >> 16], 1);
  __syncthreads();

  int cnt = lcnt[t];
  s[t] = cnt;
  __syncthreads();
  for (int d = 1; d < 256; d <<= 1) {
    int x = (t >= d) ? s[t - d] : 0;
    __syncthreads();
    s[t] += x;
    __syncthreads();
  }
  int node = b * BWD + t;
  int ex = s[t] - cnt;
  lfill[t] = ex;
  if (node < NN) {
    off[node] = e0 + ex;
    dinv[node] = rsqrtf((float)(cnt + 1));  // +1 self-loop
  }
  if (node == NN - 1) off[NN] = NE;
  __syncthreads();

  for (int i = t; i < n; i += 256) {
    unsigned p = pb[i];
    int pos = atomicAdd(&lfill[p >> 16], 1);
    stage[pos] = (unsigned short)(p & 0xffffu);
  }
  __syncthreads();
  for (int i = t; i < n; i += 256) ssrc[e0 + i] = stage[i];
}

// ---------------- agg1: wave per node, dinv[src] gather, bf16+relu out ----------------

__global__ __launch_bounds__(256) void k_agg1(const unsigned* __restrict__ hA, const float* __restrict__ dinv,
                                              const int* __restrict__ off, const unsigned short* __restrict__ ssrc,
                                              const float* __restrict__ b1, unsigned* __restrict__ act) {
  int gw = (blockIdx.x * 256 + threadIdx.x) >> 6;
  int lane = threadIdx.x & 63;
  if (gw >= NN) return;

  int c = lane & 15;
  int q = lane >> 4;
  float di = dinv[gw];

  float acc[8];
  {
    uint4 u = *((const uint4*)(hA + (size_t)gw * 64) + c);
    float m = (q == 0) ? di : 0.f;  // self: dinv[g] (x di at end -> di^2)
    acc[0] = bflo(u.x) * m; acc[1] = bfhi(u.x) * m;
    acc[2] = bflo(u.y) * m; acc[3] = bfhi(u.y) * m;
    acc[4] = bflo(u.z) * m; acc[5] = bfhi(u.z) * m;
    acc[6] = bflo(u.w) * m; acc[7] = bfhi(u.w) * m;
  }

  int e = off[gw], e1 = off[gw + 1];
  for (int e0 = e; e0 < e1; e0 += 8) {
    int ea = e0 + q, eb = e0 + 4 + q;
    int sa = (ea < e1) ? (int)ssrc[ea] : NN;
    int sb = (eb < e1) ? (int)ssrc[eb] : NN;
    float wa = (ea < e1) ? dinv[sa] : 0.f;
    float wb = (eb < e1) ? dinv[sb] : 0.f;
    uint4 ua = *((const uint4*)(hA + (size_t)sa * 64) + c);
    uint4 ub = *((const uint4*)(hA + (size_t)sb * 64) + c);
    acc[0] = fmaf(bflo(ua.x), wa, acc[0]); acc[1] = fmaf(bfhi(ua.x), wa, acc[1]);
    acc[2] = fmaf(bflo(ua.y), wa, acc[2]); acc[3] = fmaf(bfhi(ua.y), wa, acc[3]);
    acc[4] = fmaf(bflo(ua.z), wa, acc[4]); acc[5] = fmaf(bfhi(ua.z), wa, acc[5]);
    acc[6] = fmaf(bflo(ua.w), wa, acc[6]); acc[7] = fmaf(bfhi(ua.w), wa, acc[7]);
    acc[0] = fmaf(bflo(ub.x), wb, acc[0]); acc[1] = fmaf(bfhi(ub.x), wb, acc[1]);
    acc[2] = fmaf(bflo(ub.y), wb, acc[2]); acc[3] = fmaf(bfhi(ub.y), wb, acc[3]);
    acc[4] = fmaf(bflo(ub.z), wb, acc[4]); acc[5] = fmaf(bfhi(ub.z), wb, acc[5]);
    acc[6] = fmaf(bflo(ub.w), wb, acc[6]); acc[7] = fmaf(bfhi(ub.w), wb, acc[7]);
  }

#pragma unroll
  for (int j = 0; j < 8; ++j) {
    acc[j] += __shfl_xor(acc[j], 16);
    acc[j] += __shfl_xor(acc[j], 32);
  }

  if (q < 2) {
    int col0 = c * 8 + q * 4;
    float4 b4 = *(const float4*)(b1 + col0);
    float o0 = fmaxf(fmaf(acc[q * 4 + 0], di, b4.x), 0.f);
    float o1 = fmaxf(fmaf(acc[q * 4 + 1], di, b4.y), 0.f);
    float o2 = fmaxf(fmaf(acc[q * 4 + 2], di, b4.z), 0.f);
    float o3 = fmaxf(fmaf(acc[q * 4 + 3], di, b4.w), 0.f);
    uint2 p;
    p.x = bf16rne(o0) | (bf16rne(o1) << 16);
    p.y = bf16rne(o2) | (bf16rne(o3) << 16);
    *(uint2*)((unsigned*)act + (size_t)gw * 64 + c * 4 + q * 2) = p;
  }
}

// ---------------- gemm2: hB = dinv[row]*(act@W2), bf16 in/out ----------------

__global__ __launch_bounds__(256) void k_gemm2(const unsigned* __restrict__ act,
                                               const uint4* __restrict__ whf,
                                               const uint4* __restrict__ wlf,
                                               const float* __restrict__ dinv,
                                               unsigned* __restrict__ hB) {
  __shared__ float Ep[4][16][132];
  int t = threadIdx.x, w = t >> 6, l = t & 63;
  int brow = blockIdx.x * 64 + w * 16;
  int ra = brow + (l & 15);
  bool inb = ra < NN;

  short8 Ah[4];
#pragma unroll
  for (int kc = 0; kc < 4; ++kc) {
    uint4 u = make_uint4(0, 0, 0, 0);
    if (inb) u = ((const uint4*)act)[(size_t)ra * 16 + kc * 4 + (l >> 4)];
    Ah[kc] = *(short8*)&u;
  }

  f32x4 acc[8];
#pragma unroll
  for (int ct = 0; ct < 8; ++ct) acc[ct] = f32x4{0.f, 0.f, 0.f, 0.f};

#pragma unroll
  for (int kc = 0; kc < 4; ++kc) {
#pragma unroll
    for (int ct = 0; ct < 8; ++ct) {
      int fi = (ct * 4 + kc) * 64 + l;
      uint4 wh4 = whf[fi];
      uint4 wl4 = wlf[fi];
      short8 wh = *(short8*)&wh4;
      short8 wl = *(short8*)&wl4;
      acc[ct] = __builtin_amdgcn_mfma_f32_16x16x32_bf16(Ah[kc], wh, acc[ct], 0, 0, 0);
      acc[ct] = __builtin_amdgcn_mfma_f32_16x16x32_bf16(Ah[kc], wl, acc[ct], 0, 0, 0);
    }
  }

#pragma unroll
  for (int ct = 0; ct < 8; ++ct)
#pragma unroll
    for (int reg = 0; reg < 4; ++reg)
      Ep[w][(l >> 4) * 4 + reg][ct * 16 + (l & 15)] = acc[ct][reg];

  int r16 = l >> 2, cc = (l & 3) * 32;
  int R = blockIdx.x * 64 + w * 16 + r16;
  float sc = (R < NN) ? dinv[R] : 0.f;
  unsigned ub[16];
#pragma unroll
  for (int i = 0; i < 16; ++i) {
    float f0 = Ep[w][r16][cc + 2 * i] * sc;
    float f1 = Ep[w][r16][cc + 2 * i + 1] * sc;
    ub[i] = bf16rne(f0) | (bf16rne(f1) << 16);
  }
  uint4* co = (uint4*)(hB + (size_t)R * 64 + (cc >> 1));
  co[0] = make_uint4(ub[0], ub[1], ub[2], ub[3]);
  co[1] = make_uint4(ub[4], ub[5], ub[6], ub[7]);
  co[2] = make_uint4(ub[8], ub[9], ub[10], ub[11]);
  co[3] = make_uint4(ub[12], ub[13], ub[14], ub[15]);
}

// ---------------- agg2: weightless gather (hB prescaled), f32 out ----------------

__global__ __launch_bounds__(256) void k_agg2(const unsigned* __restrict__ h, const float* __restrict__ dinv,
                                              const int* __restrict__ off, const unsigned short* __restrict__ ssrc,
                                              const float* __restrict__ bias, float* __restrict__ out) {
  int gw = (blockIdx.x * 256 + threadIdx.x) >> 6;
  int lane = threadIdx.x & 63;
  if (gw >= NN) return;

  int c = lane & 15;
  int q = lane >> 4;

  float acc[8];
  {
    uint4 u = *((const uint4*)(h + (size_t)gw * 64) + c);
    float m = (q == 0) ? 1.f : 0.f;
    acc[0] = bflo(u.x) * m; acc[1] = bfhi(u.x) * m;
    acc[2] = bflo(u.y) * m; acc[3] = bfhi(u.y) * m;
    acc[4] = bflo(u.z) * m; acc[5] = bfhi(u.z) * m;
    acc[6] = bflo(u.w) * m; acc[7] = bfhi(u.w) * m;
  }

  int e = off[gw], e1 = off[gw + 1];
  for (int e0 = e; e0 < e1; e0 += 8) {
    int ea = e0 + q;
    int eb = e0 + 4 + q;
    int sa = (ea < e1) ? (int)ssrc[ea] : NN;
    int sb = (eb < e1) ? (int)ssrc[eb] : NN;
    uint4 ua = *((const uint4*)(h + (size_t)sa * 64) + c);
    uint4 ub = *((const uint4*)(h + (size_t)sb * 64) + c);
    acc[0] += bflo(ua.x); acc[1] += bfhi(ua.x);
    acc[2] += bflo(ua.y); acc[3] += bfhi(ua.y);
    acc[4] += bflo(ua.z); acc[5] += bfhi(ua.z);
    acc[6] += bflo(ua.w); acc[7] += bfhi(ua.w);
    acc[0] += bflo(ub.x); acc[1] += bfhi(ub.x);
    acc[2] += bflo(ub.y); acc[3] += bfhi(ub.y);
    acc[4] += bflo(ub.z); acc[5] += bfhi(ub.z);
    acc[6] += bflo(ub.w); acc[7] += bfhi(ub.w);
  }

#pragma unroll
  for (int j = 0; j < 8; ++j) {
    acc[j] += __shfl_xor(acc[j], 16);
    acc[j] += __shfl_xor(acc[j], 32);
  }

  if (q < 2) {
    float di = dinv[gw];
    int col0 = c * 8 + q * 4;
    float4 b4 = *(const float4*)(bias + col0);
    float4 o;
    o.x = fmaf(acc[q * 4 + 0], di, b4.x);
    o.y = fmaf(acc[q * 4 + 1], di, b4.y);
    o.z = fmaf(acc[q * 4 + 2], di, b4.z);
    o.w = fmaf(acc[q * 4 + 3], di, b4.w);
    *(float4*)(out + (size_t)gw * DF + col0) = o;
  }
}

// ---------------- launcher ----------------

extern "C" void kernel_launch(void* const* d_in, const int* in_sizes, int n_in,
                              void* d_out, int out_size, void* d_ws, size_t ws_size,
                              hipStream_t stream) {
  const float* x  = (const float*)d_in[0];
  const int*   ei = (const int*)d_in[1];
  const float* W1 = (const float*)d_in[2];
  const float* b1 = (const float*)d_in[3];
  const float* W2 = (const float*)d_in[4];
  const float* b2 = (const float*)d_in[5];
  float* out = (float*)d_out;

  char* ws = (char*)d_ws;
  unsigned* hA    = (unsigned*)ws; ws += (size_t)MROWS * 64 * 4;        // bf16(X@W1), unscaled
  unsigned* act   = (unsigned*)ws; ws += (size_t)MROWS * 64 * 4;        // bf16 relu(layer1)
  unsigned* hB    = (unsigned*)ws; ws += (size_t)MROWS * 64 * 4;        // dinv*(act@W2)
  unsigned* pairs = (unsigned*)ws; ws += (size_t)NBKT * BSTRIDE * 4;
  uint4* whf = (uint4*)ws;  ws += (size_t)4096 * 16;
  uint4* wlf = (uint4*)ws;  ws += (size_t)4096 * 16;
  int*   off  = (int*)ws;   ws += (size_t)(NN + 1) * 4;
  int*   gfill= (int*)ws;   ws += (size_t)NBKT * CPAD * 4;
  float* dinv = (float*)ws; ws += (size_t)NN * 4;
  unsigned short* ssrc = (unsigned short*)ws; ws += ((size_t)NE + 16) * 2;

  k_wz<<<17, 256, 0, stream>>>(W1, W2, whf, wlf, gfill);
  k_sg<<<NSB + GG, 256, 0, stream>>>(ei, gfill, pairs, x, whf, wlf, hA);
  k_build<<<NBKT, 256, 0, stream>>>(pairs, gfill, off, dinv, ssrc);
  k_agg1<<<(NN * 64 + 255) / 256, 256, 0, stream>>>(hA, dinv, off, ssrc, b1, act);
  k_gemm2<<<GG, 256, 0, stream>>>(act, whf + 2048, wlf + 2048, dinv, hB);
  k_agg2<<<(NN * 64 + 255) / 256, 256, 0, stream>>>(hB, dinv, off, ssrc, b2, out);
}

// Round 15
// 113.583 us; speedup vs baseline: 1.4895x; 1.0913x over previous
//
#include <hip/hip_runtime.h>

#define NN 50000
#define NE 640000
#define DF 128
#define BSH 8
#define BWD 256                          // nodes per bucket
#define NBKT 196                         // ceil(NN/BWD)
#define BSTRIDE 8192                     // per-bucket capacity (mean 3265)
#define CPAD 16                          // ints per global counter (one 64B line)
#define EPB 8192                         // edges per scatter block
#define NSB ((NE + EPB - 1) / EPB)       // 79 scatter blocks
#define MROWS 50048                      // 782*64 padded rows
#define GG 782                           // gemm row tiles

typedef __attribute__((ext_vector_type(8))) short short8;
typedef __attribute__((ext_vector_type(4))) float f32x4;

__device__ inline unsigned bf16rne(float f) {
  unsigned u = __float_as_uint(f);
  return (u + 0x7fff + ((u >> 16) & 1)) >> 16;
}
__device__ inline float bflo(unsigned u) { return __uint_as_float(u << 16); }
__device__ inline float bfhi(unsigned u) { return __uint_as_float(u & 0xffff0000u); }

// ---------------- wpack + gfill zero ----------------

__global__ __launch_bounds__(256) void k_wz(const float* __restrict__ W1, const float* __restrict__ W2,
                                            uint4* __restrict__ whf, uint4* __restrict__ wlf,
                                            int* __restrict__ gfill) {
  if (blockIdx.x == 16) {
    for (int i = threadIdx.x; i < NBKT * CPAD; i += 256) gfill[i] = 0;
    return;
  }
  int idx = blockIdx.x * 256 + threadIdx.x;  // 0..4095
  int m = idx >> 11;
  int r = idx & 2047;
  int ct = r >> 8, kc = (r >> 6) & 3, l = r & 63;
  const float* W = m ? W2 : W1;
  unsigned hi[8], lo[8];
#pragma unroll
  for (int j = 0; j < 8; ++j) {
    int k = kc * 32 + (l >> 4) * 8 + j;
    int c = ct * 16 + (l & 15);
    float w = W[k * DF + c];
    unsigned h = bf16rne(w);
    hi[j] = h;
    lo[j] = bf16rne(w - bflo(h));
  }
  uint4 H, L;
  H.x = hi[0] | (hi[1] << 16); H.y = hi[2] | (hi[3] << 16);
  H.z = hi[4] | (hi[5] << 16); H.w = hi[6] | (hi[7] << 16);
  L.x = lo[0] | (lo[1] << 16); L.y = lo[2] | (lo[3] << 16);
  L.z = lo[4] | (lo[5] << 16); L.w = lo[6] | (lo[7] << 16);
  whf[idx] = H;
  wlf[idx] = L;
}

// ---------------- fused: bucketed scatter || gemm1 (hA = bf16(X@W1), unscaled) ----------------

struct ScatSh {
  int cnt[NBKT], cur[NBKT], gbase[NBKT];
  int scan[256];
  unsigned stage[EPB];
};
struct GemmSh { float Ep[4][16][132]; };
union SgSh { ScatSh s; GemmSh g; };

__global__ __launch_bounds__(256) void k_sg(const int* __restrict__ ei, int* __restrict__ gfill,
                                            unsigned* __restrict__ pairs,
                                            const float* __restrict__ X,
                                            const uint4* __restrict__ whf, const uint4* __restrict__ wlf,
                                            unsigned* __restrict__ hA) {
  __shared__ SgSh sh;
  int t = threadIdx.x;

  if (blockIdx.x < NSB) {
    int e0 = blockIdx.x * EPB;
    for (int i = t; i < NBKT; i += 256) sh.s.cnt[i] = 0;
    __syncthreads();

    unsigned pk[32];
    int bk[32];
#pragma unroll
    for (int i = 0; i < 32; ++i) {
      int e = e0 + i * 256 + t;
      if (e < NE) {
        int s = ei[e], d = ei[NE + e];
        bk[i] = d >> BSH;
        pk[i] = (unsigned)s | ((unsigned)(d & (BWD - 1)) << 16);
        atomicAdd(&sh.s.cnt[bk[i]], 1);
      } else {
        bk[i] = -1;
      }
    }
    __syncthreads();

    int v = (t < NBKT) ? sh.s.cnt[t] : 0;
    sh.s.scan[t] = v;
    __syncthreads();
    for (int d = 1; d < 256; d <<= 1) {
      int x2 = (t >= d) ? sh.s.scan[t - d] : 0;
      __syncthreads();
      sh.s.scan[t] += x2;
      __syncthreads();
    }
    if (t < NBKT) {
      int start = sh.s.scan[t] - v;
      sh.s.cnt[t] = start;
      sh.s.cur[t] = start;
      sh.s.gbase[t] = (v > 0) ? atomicAdd(&gfill[t * CPAD], v) : 0;
    }
    __syncthreads();

#pragma unroll
    for (int i = 0; i < 32; ++i) {
      if (bk[i] >= 0) {
        int pos = atomicAdd(&sh.s.cur[bk[i]], 1);
        sh.s.stage[pos] = pk[i];
      }
    }
    __syncthreads();

    int wv = t >> 6, ln = t & 63;
    for (int b = wv; b < NBKT; b += 4) {
      int start = sh.s.cnt[b];
      int end = sh.s.cur[b];
      int gb = sh.s.gbase[b];
      unsigned* pb = pairs + (size_t)b * BSTRIDE;
      for (int i = start + ln; i < end; i += 64) {
        int go = gb + (i - start);
        if (go < BSTRIDE) pb[go] = sh.s.stage[i];
      }
    }
  } else {
    // gemm1: MFMA hi/lo, f32 A, unscaled bf16 out
    int w = t >> 6, l = t & 63;
    int brow = (blockIdx.x - NSB) * 64 + w * 16;
    int ra = brow + (l & 15);
    bool inb = ra < NN;

    short8 Ah[4], Al[4];
#pragma unroll
    for (int kc = 0; kc < 4; ++kc) {
      float f[8] = {0.f, 0.f, 0.f, 0.f, 0.f, 0.f, 0.f, 0.f};
      if (inb) {
        const float* A = X + (size_t)ra * DF + kc * 32 + (l >> 4) * 8;
        float4 p = *(const float4*)A;
        float4 qq = *(const float4*)(A + 4);
        f[0] = p.x; f[1] = p.y; f[2] = p.z; f[3] = p.w;
        f[4] = qq.x; f[5] = qq.y; f[6] = qq.z; f[7] = qq.w;
      }
      unsigned hh[8], ll[8];
#pragma unroll
      for (int j = 0; j < 8; ++j) {
        hh[j] = bf16rne(f[j]);
        ll[j] = bf16rne(f[j] - bflo(hh[j]));
      }
      uint4 H, L;
      H.x = hh[0] | (hh[1] << 16); H.y = hh[2] | (hh[3] << 16);
      H.z = hh[4] | (hh[5] << 16); H.w = hh[6] | (hh[7] << 16);
      L.x = ll[0] | (ll[1] << 16); L.y = ll[2] | (ll[3] << 16);
      L.z = ll[4] | (ll[5] << 16); L.w = ll[6] | (ll[7] << 16);
      Ah[kc] = *(short8*)&H;
      Al[kc] = *(short8*)&L;
    }

    f32x4 acc[8];
#pragma unroll
    for (int ct = 0; ct < 8; ++ct) acc[ct] = f32x4{0.f, 0.f, 0.f, 0.f};

#pragma unroll
    for (int kc = 0; kc < 4; ++kc) {
#pragma unroll
      for (int ct = 0; ct < 8; ++ct) {
        int fi = (ct * 4 + kc) * 64 + l;
        uint4 wh4 = whf[fi];
        uint4 wl4 = wlf[fi];
        short8 wh = *(short8*)&wh4;
        short8 wl = *(short8*)&wl4;
        acc[ct] = __builtin_amdgcn_mfma_f32_16x16x32_bf16(Ah[kc], wh, acc[ct], 0, 0, 0);
        acc[ct] = __builtin_amdgcn_mfma_f32_16x16x32_bf16(Ah[kc], wl, acc[ct], 0, 0, 0);
        acc[ct] = __builtin_amdgcn_mfma_f32_16x16x32_bf16(Al[kc], wh, acc[ct], 0, 0, 0);
      }
    }

#pragma unroll
    for (int ct = 0; ct < 8; ++ct)
#pragma unroll
      for (int reg = 0; reg < 4; ++reg)
        sh.g.Ep[w][(l >> 4) * 4 + reg][ct * 16 + (l & 15)] = acc[ct][reg];

    int r16 = l >> 2, cc = (l & 3) * 32;
    int R = (blockIdx.x - NSB) * 64 + w * 16 + r16;
    float sc = (R < NN) ? 1.f : 0.f;
    unsigned ub[16];
#pragma unroll
    for (int i = 0; i < 16; ++i) {
      float f0 = sh.g.Ep[w][r16][cc + 2 * i] * sc;
      float f1 = sh.g.Ep[w][r16][cc + 2 * i + 1] * sc;
      ub[i] = bf16rne(f0) | (bf16rne(f1) << 16);
    }
    uint4* co = (uint4*)(hA + (size_t)R * 64 + (cc >> 1));
    co[0] = make_uint4(ub[0], ub[1], ub[2], ub[3]);
    co[1] = make_uint4(ub[4], ub[5], ub[6], ub[7]);
    co[2] = make_uint4(ub[8], ub[9], ub[10], ub[11]);
    co[3] = make_uint4(ub[12], ub[13], ub[14], ub[15]);
  }
}

// ---------------- build (512 thr): bucket-prefix + LDS counting sort ----------------

__global__ __launch_bounds__(512) void k_build(const unsigned* __restrict__ pairs,
                                               const int* __restrict__ gfill,
                                               int* __restrict__ off, float* __restrict__ dinv,
                                               unsigned short* __restrict__ ssrc) {
  __shared__ int lcnt[BWD];
  __shared__ int lfill[BWD];
  __shared__ int s[BWD];
  __shared__ int red[512];
  __shared__ unsigned short stage[BSTRIDE];
  int b = blockIdx.x, t = threadIdx.x;

  int part = 0;
  for (int j = t; j < b; j += 512) part += min(gfill[j * CPAD], BSTRIDE);
  red[t] = part;
  __syncthreads();
  for (int d = 256; d > 0; d >>= 1) {
    if (t < d) red[t] += red[t + d];
    __syncthreads();
  }
  int e0 = red[0];
  int n = min(gfill[b * CPAD], BSTRIDE);
  const unsigned* pb = pairs + (size_t)b * BSTRIDE;

  if (t < BWD) lcnt[t] = 0;
  __syncthreads();
  for (int i = t; i < n; i += 512) atomicAdd(&lcnt[pb[i] >> 16], 1);
  __syncthreads();

  int cnt = (t < BWD) ? lcnt[t] : 0;
  if (t < BWD) s[t] = cnt;
  __syncthreads();
  for (int d = 1; d < BWD; d <<= 1) {
    int x = (t >= d && t < BWD) ? s[t - d] : 0;
    __syncthreads();
    if (t < BWD) s[t] += x;
    __syncthreads();
  }
  int node = b * BWD + t;
  if (t < BWD) {
    int ex = s[t] - cnt;
    lfill[t] = ex;
    if (node < NN) {
      off[node] = e0 + ex;
      dinv[node] = rsqrtf((float)(cnt + 1));  // +1 self-loop
    }
    if (node == NN - 1) {
      off[NN] = NE;
      dinv[NN] = 0.f;  // sentinel row: zero weight
    }
  }
  __syncthreads();

  for (int i = t; i < n; i += 512) {
    unsigned p = pb[i];
    int pos = atomicAdd(&lfill[p >> 16], 1);
    stage[pos] = (unsigned short)(p & 0xffffu);
  }
  __syncthreads();
  for (int i = t; i < n; i += 512) ssrc[e0 + i] = stage[i];
  if (b == NBKT - 1) {
    for (int i = t; i < 32; i += 512) ssrc[NE + i] = (unsigned short)NN;  // sentinel pad
  }
}

// ---------------- agg1: wave/node, 16 edges/iter (4 row-gathers in flight) ----------------

__global__ __launch_bounds__(256) void k_agg1(const unsigned* __restrict__ hA, const float* __restrict__ dinv,
                                              const int* __restrict__ off, const unsigned short* __restrict__ ssrc,
                                              const float* __restrict__ b1, unsigned* __restrict__ act) {
  int gw = (blockIdx.x * 256 + threadIdx.x) >> 6;
  int lane = threadIdx.x & 63;
  if (gw >= NN) return;

  int c = lane & 15;
  int q = lane >> 4;
  float di = dinv[gw];

  float acc[8];
  {
    uint4 u = *((const uint4*)(hA + (size_t)gw * 64) + c);
    float m = (q == 0) ? di : 0.f;  // self: dinv[g] (x di at end -> di^2)
    acc[0] = bflo(u.x) * m; acc[1] = bfhi(u.x) * m;
    acc[2] = bflo(u.y) * m; acc[3] = bfhi(u.y) * m;
    acc[4] = bflo(u.z) * m; acc[5] = bfhi(u.z) * m;
    acc[6] = bflo(u.w) * m; acc[7] = bfhi(u.w) * m;
  }

  int e = off[gw], e1 = off[gw + 1];
  for (int e0 = e; e0 < e1; e0 += 16) {
    int i0 = e0 + q, i1 = i0 + 4, i2 = i0 + 8, i3 = i0 + 12;
    int s0 = (int)ssrc[i0]; if (i0 >= e1) s0 = NN;   // clamp to zero row (L1-hot)
    int s1 = (int)ssrc[i1]; if (i1 >= e1) s1 = NN;
    int s2 = (int)ssrc[i2]; if (i2 >= e1) s2 = NN;
    int s3 = (int)ssrc[i3]; if (i3 >= e1) s3 = NN;
    float w0 = dinv[s0], w1 = dinv[s1], w2 = dinv[s2], w3 = dinv[s3];  // dinv[NN]=0
    uint4 u0 = *((const uint4*)(hA + (size_t)s0 * 64) + c);
    uint4 u1 = *((const uint4*)(hA + (size_t)s1 * 64) + c);
    uint4 u2 = *((const uint4*)(hA + (size_t)s2 * 64) + c);
    uint4 u3 = *((const uint4*)(hA + (size_t)s3 * 64) + c);
    acc[0] = fmaf(bflo(u0.x), w0, acc[0]); acc[1] = fmaf(bfhi(u0.x), w0, acc[1]);
    acc[2] = fmaf(bflo(u0.y), w0, acc[2]); acc[3] = fmaf(bfhi(u0.y), w0, acc[3]);
    acc[4] = fmaf(bflo(u0.z), w0, acc[4]); acc[5] = fmaf(bfhi(u0.z), w0, acc[5]);
    acc[6] = fmaf(bflo(u0.w), w0, acc[6]); acc[7] = fmaf(bfhi(u0.w), w0, acc[7]);
    acc[0] = fmaf(bflo(u1.x), w1, acc[0]); acc[1] = fmaf(bfhi(u1.x), w1, acc[1]);
    acc[2] = fmaf(bflo(u1.y), w1, acc[2]); acc[3] = fmaf(bfhi(u1.y), w1, acc[3]);
    acc[4] = fmaf(bflo(u1.z), w1, acc[4]); acc[5] = fmaf(bfhi(u1.z), w1, acc[5]);
    acc[6] = fmaf(bflo(u1.w), w1, acc[6]); acc[7] = fmaf(bfhi(u1.w), w1, acc[7]);
    acc[0] = fmaf(bflo(u2.x), w2, acc[0]); acc[1] = fmaf(bfhi(u2.x), w2, acc[1]);
    acc[2] = fmaf(bflo(u2.y), w2, acc[2]); acc[3] = fmaf(bfhi(u2.y), w2, acc[3]);
    acc[4] = fmaf(bflo(u2.z), w2, acc[4]); acc[5] = fmaf(bfhi(u2.z), w2, acc[5]);
    acc[6] = fmaf(bflo(u2.w), w2, acc[6]); acc[7] = fmaf(bfhi(u2.w), w2, acc[7]);
    acc[0] = fmaf(bflo(u3.x), w3, acc[0]); acc[1] = fmaf(bfhi(u3.x), w3, acc[1]);
    acc[2] = fmaf(bflo(u3.y), w3, acc[2]); acc[3] = fmaf(bfhi(u3.y), w3, acc[3]);
    acc[4] = fmaf(bflo(u3.z), w3, acc[4]); acc[5] = fmaf(bfhi(u3.z), w3, acc[5]);
    acc[6] = fmaf(bflo(u3.w), w3, acc[6]); acc[7] = fmaf(bfhi(u3.w), w3, acc[7]);
  }

#pragma unroll
  for (int j = 0; j < 8; ++j) {
    acc[j] += __shfl_xor(acc[j], 16);
    acc[j] += __shfl_xor(acc[j], 32);
  }

  if (q < 2) {
    int col0 = c * 8 + q * 4;
    float4 b4 = *(const float4*)(b1 + col0);
    float o0 = fmaxf(fmaf(acc[q * 4 + 0], di, b4.x), 0.f);
    float o1 = fmaxf(fmaf(acc[q * 4 + 1], di, b4.y), 0.f);
    float o2 = fmaxf(fmaf(acc[q * 4 + 2], di, b4.z), 0.f);
    float o3 = fmaxf(fmaf(acc[q * 4 + 3], di, b4.w), 0.f);
    uint2 p;
    p.x = bf16rne(o0) | (bf16rne(o1) << 16);
    p.y = bf16rne(o2) | (bf16rne(o3) << 16);
    *(uint2*)((unsigned*)act + (size_t)gw * 64 + c * 4 + q * 2) = p;
  }
}

// ---------------- gemm2: hB = dinv[row]*(act@W2), bf16 in/out ----------------

__global__ __launch_bounds__(256) void k_gemm2(const unsigned* __restrict__ act,
                                               const uint4* __restrict__ whf,
                                               const uint4* __restrict__ wlf,
                                               const float* __restrict__ dinv,
                                               unsigned* __restrict__ hB) {
  __shared__ float Ep[4][16][132];
  int t = threadIdx.x, w = t >> 6, l = t & 63;
  int brow = blockIdx.x * 64 + w * 16;
  int ra = brow + (l & 15);
  bool inb = ra < NN;

  short8 Ah[4];
#pragma unroll
  for (int kc = 0; kc < 4; ++kc) {
    uint4 u = make_uint4(0, 0, 0, 0);
    if (inb) u = ((const uint4*)act)[(size_t)ra * 16 + kc * 4 + (l >> 4)];
    Ah[kc] = *(short8*)&u;
  }

  f32x4 acc[8];
#pragma unroll
  for (int ct = 0; ct < 8; ++ct) acc[ct] = f32x4{0.f, 0.f, 0.f, 0.f};

#pragma unroll
  for (int kc = 0; kc < 4; ++kc) {
#pragma unroll
    for (int ct = 0; ct < 8; ++ct) {
      int fi = (ct * 4 + kc) * 64 + l;
      uint4 wh4 = whf[fi];
      uint4 wl4 = wlf[fi];
      short8 wh = *(short8*)&wh4;
      short8 wl = *(short8*)&wl4;
      acc[ct] = __builtin_amdgcn_mfma_f32_16x16x32_bf16(Ah[kc], wh, acc[ct], 0, 0, 0);
      acc[ct] = __builtin_amdgcn_mfma_f32_16x16x32_bf16(Ah[kc], wl, acc[ct], 0, 0, 0);
    }
  }

#pragma unroll
  for (int ct = 0; ct < 8; ++ct)
#pragma unroll
    for (int reg = 0; reg < 4; ++reg)
      Ep[w][(l >> 4) * 4 + reg][ct * 16 + (l & 15)] = acc[ct][reg];

  int r16 = l >> 2, cc = (l & 3) * 32;
  int R = blockIdx.x * 64 + w * 16 + r16;
  float sc = (R < NN) ? dinv[R] : 0.f;
  unsigned ub[16];
#pragma unroll
  for (int i = 0; i < 16; ++i) {
    float f0 = Ep[w][r16][cc + 2 * i] * sc;
    float f1 = Ep[w][r16][cc + 2 * i + 1] * sc;
    ub[i] = bf16rne(f0) | (bf16rne(f1) << 16);
  }
  uint4* co = (uint4*)(hB + (size_t)R * 64 + (cc >> 1));
  co[0] = make_uint4(ub[0], ub[1], ub[2], ub[3]);
  co[1] = make_uint4(ub[4], ub[5], ub[6], ub[7]);
  co[2] = make_uint4(ub[8], ub[9], ub[10], ub[11]);
  co[3] = make_uint4(ub[12], ub[13], ub[14], ub[15]);
}

// ---------------- agg2: weightless, 16 edges/iter, f32 out ----------------

__global__ __launch_bounds__(256) void k_agg2(const unsigned* __restrict__ h, const float* __restrict__ dinv,
                                              const int* __restrict__ off, const unsigned short* __restrict__ ssrc,
                                              const float* __restrict__ bias, float* __restrict__ out) {
  int gw = (blockIdx.x * 256 + threadIdx.x) >> 6;
  int lane = threadIdx.x & 63;
  if (gw >= NN) return;

  int c = lane & 15;
  int q = lane >> 4;

  float acc[8];
  {
    uint4 u = *((const uint4*)(h + (size_t)gw * 64) + c);
    float m = (q == 0) ? 1.f : 0.f;
    acc[0] = bflo(u.x) * m; acc[1] = bfhi(u.x) * m;
    acc[2] = bflo(u.y) * m; acc[3] = bfhi(u.y) * m;
    acc[4] = bflo(u.z) * m; acc[5] = bfhi(u.z) * m;
    acc[6] = bflo(u.w) * m; acc[7] = bfhi(u.w) * m;
  }

  int e = off[gw], e1 = off[gw + 1];
  for (int e0 = e; e0 < e1; e0 += 16) {
    int i0 = e0 + q, i1 = i0 + 4, i2 = i0 + 8, i3 = i0 + 12;
    int s0 = (int)ssrc[i0]; if (i0 >= e1) s0 = NN;   // row NN = zeros (L1-hot)
    int s1 = (int)ssrc[i1]; if (i1 >= e1) s1 = NN;
    int s2 = (int)ssrc[i2]; if (i2 >= e1) s2 = NN;
    int s3 = (int)ssrc[i3]; if (i3 >= e1) s3 = NN;
    uint4 u0 = *((const uint4*)(h + (size_t)s0 * 64) + c);
    uint4 u1 = *((const uint4*)(h + (size_t)s1 * 64) + c);
    uint4 u2 = *((const uint4*)(h + (size_t)s2 * 64) + c);
    uint4 u3 = *((const uint4*)(h + (size_t)s3 * 64) + c);
    acc[0] += bflo(u0.x); acc[1] += bfhi(u0.x);
    acc[2] += bflo(u0.y); acc[3] += bfhi(u0.y);
    acc[4] += bflo(u0.z); acc[5] += bfhi(u0.z);
    acc[6] += bflo(u0.w); acc[7] += bfhi(u0.w);
    acc[0] += bflo(u1.x); acc[1] += bfhi(u1.x);
    acc[2] += bflo(u1.y); acc[3] += bfhi(u1.y);
    acc[4] += bflo(u1.z); acc[5] += bfhi(u1.z);
    acc[6] += bflo(u1.w); acc[7] += bfhi(u1.w);
    acc[0] += bflo(u2.x); acc[1] += bfhi(u2.x);
    acc[2] += bflo(u2.y); acc[3] += bfhi(u2.y);
    acc[4] += bflo(u2.z); acc[5] += bfhi(u2.z);
    acc[6] += bflo(u2.w); acc[7] += bfhi(u2.w);
    acc[0] += bflo(u3.x); acc[1] += bfhi(u3.x);
    acc[2] += bflo(u3.y); acc[3] += bfhi(u3.y);
    acc[4] += bflo(u3.z); acc[5] += bfhi(u3.z);
    acc[6] += bflo(u3.w); acc[7] += bfhi(u3.w);
  }

#pragma unroll
  for (int j = 0; j < 8; ++j) {
    acc[j] += __shfl_xor(acc[j], 16);
    acc[j] += __shfl_xor(acc[j], 32);
  }

  if (q < 2) {
    float di = dinv[gw];
    int col0 = c * 8 + q * 4;
    float4 b4 = *(const float4*)(bias + col0);
    float4 o;
    o.x = fmaf(acc[q * 4 + 0], di, b4.x);
    o.y = fmaf(acc[q * 4 + 1], di, b4.y);
    o.z = fmaf(acc[q * 4 + 2], di, b4.z);
    o.w = fmaf(acc[q * 4 + 3], di, b4.w);
    *(float4*)(out + (size_t)gw * DF + col0) = o;
  }
}

// ---------------- launcher ----------------

extern "C" void kernel_launch(void* const* d_in, const int* in_sizes, int n_in,
                              void* d_out, int out_size, void* d_ws, size_t ws_size,
                              hipStream_t stream) {
  const float* x  = (const float*)d_in[0];
  const int*   ei = (const int*)d_in[1];
  const float* W1 = (const float*)d_in[2];
  const float* b1 = (const float*)d_in[3];
  const float* W2 = (const float*)d_in[4];
  const float* b2 = (const float*)d_in[5];
  float* out = (float*)d_out;

  char* ws = (char*)d_ws;
  unsigned* hA    = (unsigned*)ws; ws += (size_t)MROWS * 64 * 4;        // bf16(X@W1), unscaled
  unsigned* act   = (unsigned*)ws; ws += (size_t)MROWS * 64 * 4;        // bf16 relu(layer1)
  unsigned* hB    = (unsigned*)ws; ws += (size_t)MROWS * 64 * 4;        // dinv*(act@W2)
  unsigned* pairs = (unsigned*)ws; ws += (size_t)NBKT * BSTRIDE * 4;
  uint4* whf = (uint4*)ws;  ws += (size_t)4096 * 16;
  uint4* wlf = (uint4*)ws;  ws += (size_t)4096 * 16;
  int*   off  = (int*)ws;   ws += (size_t)(NN + 1) * 4;
  int*   gfill= (int*)ws;   ws += (size_t)NBKT * CPAD * 4;
  float* dinv = (float*)ws; ws += (size_t)(NN + 2) * 4;                 // +1 sentinel slot
  unsigned short* ssrc = (unsigned short*)ws; ws += ((size_t)NE + 64) * 2;  // +32 sentinel pad

  k_wz<<<17, 256, 0, stream>>>(W1, W2, whf, wlf, gfill);
  k_sg<<<NSB + GG, 256, 0, stream>>>(ei, gfill, pairs, x, whf, wlf, hA);
  k_build<<<NBKT, 512, 0, stream>>>(pairs, gfill, off, dinv, ssrc);
  k_agg1<<<(NN * 64 + 255) / 256, 256, 0, stream>>>(hA, dinv, off, ssrc, b1, act);
  k_gemm2<<<GG, 256, 0, stream>>>(act, whf + 2048, wlf + 2048, dinv, hB);
  k_agg2<<<(NN * 64 + 255) / 256, 256, 0, stream>>>(hB, dinv, off, ssrc, b2, out);
}